// Round 9
// baseline (99.387 us; speedup 1.0000x reference)
//
#include <hip/hip_runtime.h>
#include <hip/hip_bf16.h>

#define LOG2E 1.4426950408889634f
#define PI_D  3.14159265358979323846

typedef __attribute__((ext_vector_type(8))) short short8b;   // 8 bf16 (4 VGPR)
typedef __attribute__((ext_vector_type(4))) short short4b;   // 4 bf16 (8 B)
typedef __attribute__((ext_vector_type(4))) float f32x4;
typedef __attribute__((ext_vector_type(2))) float f32x2;

__device__ __forceinline__ float fast_exp2(float x) {
#if __has_builtin(__builtin_amdgcn_exp2f)
  return __builtin_amdgcn_exp2f(x);
#else
  return exp2f(x);
#endif
}
__device__ __forceinline__ float fast_rcp(float x) {
#if __has_builtin(__builtin_amdgcn_rcpf)
  return __builtin_amdgcn_rcpf(x);
#else
  return 1.0f / x;
#endif
}
__device__ __forceinline__ short f2bf(float f) {
  __hip_bfloat16 h = __float2bfloat16(f);
  return *reinterpret_cast<short*>(&h);
}

// ---------------------------------------------------------------------------
// Stage 0: fit degree-14 interpolating polynomial to tanh on [0, 4.5] at
// Chebyshev nodes (Lagrange -> monomial, f64, fully static register arrays).
// Runs every launch (deterministic).  Error ~1e-4 (< proven-safe 4.9e-4).
// ---------------------------------------------------------------------------
__global__ __launch_bounds__(64) void fit_kernel(float* __restrict__ Cf) {
  int k = threadIdx.x;
  __shared__ double col[15][16];
  if (k < 15) {
    double xk = 2.25 * (1.0 + cos((2.0 * k + 1.0) * (PI_D / 30.0)));
    double fk = tanh(xk);
    double c[15];
#pragma unroll
    for (int i = 0; i < 15; ++i) c[i] = 0.0;
    c[0] = 1.0;
    double denom = 1.0;
#pragma unroll
    for (int j = 0; j < 15; ++j) {
      if (j != k) {
        double xj = 2.25 * (1.0 + cos((2.0 * j + 1.0) * (PI_D / 30.0)));
        denom *= (xk - xj);
#pragma unroll
        for (int i = 14; i >= 1; --i) c[i] = c[i - 1] - xj * c[i];
        c[0] = -xj * c[0];
      }
    }
    double wgt = fk / denom;
#pragma unroll
    for (int i = 0; i < 15; ++i) col[i][k] = c[i] * wgt;
  }
  __syncthreads();
  if (k < 15) {
    double s = 0.0;
#pragma unroll
    for (int j = 0; j < 15; ++j) s += col[k][j];
    Cf[k] = (float)s;
  }
}

// ---------------------------------------------------------------------------
// Stage 1: O = relu(X @ W^T + bias) via bf16 MFMA (f32 accumulate).
// Tile 128x64, 4 waves (2x2), per-wave 64x32 = 4x2 frags of 16x16.
// ---------------------------------------------------------------------------
__global__ __launch_bounds__(256) void gemm_mfma_kernel(
    const float* __restrict__ Xa, const float* __restrict__ Wa,
    const float* __restrict__ ba, float* __restrict__ Oa,
    const float* __restrict__ Xb, const float* __restrict__ Wb,
    const float* __restrict__ bb, float* __restrict__ Ob) {
  const float* X = blockIdx.z ? Xb : Xa;
  const float* W = blockIdx.z ? Wb : Wa;
  const float* bias = blockIdx.z ? bb : ba;
  float* O = blockIdx.z ? Ob : Oa;

  __shared__ __align__(16) short As[128 * 40];
  __shared__ __align__(16) short Ws[64 * 40];

  int t = threadIdx.x;
  int m0 = blockIdx.x * 128, n0 = blockIdx.y * 64;
  int l = t & 63, w = t >> 6;
  int wm = (w >> 1) * 64, wn = (w & 1) * 32;
  int lr = l & 15, ko = (l >> 4) * 8;

  f32x4 acc[4][2];
#pragma unroll
  for (int m = 0; m < 4; ++m)
#pragma unroll
    for (int n = 0; n < 2; ++n) acc[m][n] = f32x4{0.f, 0.f, 0.f, 0.f};

  for (int k0 = 0; k0 < 512; k0 += 32) {
#pragma unroll
    for (int s = 0; s < 4; ++s) {
      int slot = t + s * 256;
      int row = slot >> 3, q = (slot & 7) << 2;
      float4 v = *reinterpret_cast<const float4*>(&X[(m0 + row) * 512 + k0 + q]);
      short4b sv = {f2bf(v.x), f2bf(v.y), f2bf(v.z), f2bf(v.w)};
      *reinterpret_cast<short4b*>(&As[row * 40 + q]) = sv;
    }
#pragma unroll
    for (int s = 0; s < 2; ++s) {
      int slot = t + s * 256;
      int row = slot >> 3, q = (slot & 7) << 2;
      float4 v = *reinterpret_cast<const float4*>(&W[(n0 + row) * 512 + k0 + q]);
      short4b sv = {f2bf(v.x), f2bf(v.y), f2bf(v.z), f2bf(v.w)};
      *reinterpret_cast<short4b*>(&Ws[row * 40 + q]) = sv;
    }
    __syncthreads();

    short8b afr[4], bfr[2];
#pragma unroll
    for (int m = 0; m < 4; ++m)
      afr[m] = *reinterpret_cast<const short8b*>(&As[(wm + m * 16 + lr) * 40 + ko]);
#pragma unroll
    for (int n = 0; n < 2; ++n)
      bfr[n] = *reinterpret_cast<const short8b*>(&Ws[(wn + n * 16 + lr) * 40 + ko]);
#pragma unroll
    for (int m = 0; m < 4; ++m)
#pragma unroll
      for (int n = 0; n < 2; ++n)
        acc[m][n] = __builtin_amdgcn_mfma_f32_16x16x32_bf16(afr[m], bfr[n], acc[m][n], 0, 0, 0);
    __syncthreads();
  }

#pragma unroll
  for (int n = 0; n < 2; ++n) {
    int col = n0 + wn + n * 16 + lr;
    float bv = bias[col];
#pragma unroll
    for (int m = 0; m < 4; ++m) {
      int rbase = m0 + wm + m * 16 + (l >> 4) * 4;
#pragma unroll
      for (int r = 0; r < 4; ++r) {
        float v = acc[m][n][r] + bv;
        O[(rbase + r) * 512 + col] = v > 0.f ? v : 0.f;
      }
    }
  }
}

// ---------------------------------------------------------------------------
// Stage 1.5: per (bh, quad-of-4-j) compact nonzero B entries, QUAD-interleaved
// entry[s][jj] (jj = j&3), zero-padded to quad max (rounded even).
// Pair = (b_raw, qm): qm = q[c] with low 8 mantissa bits = c<<2 (byte offset
// into the A row; rel perturb 3e-5).  Zero pads contribute exactly 0 (q=0).
// grid 512 = (bh x 8 jblk); 256 thr = 32 j x 8 scanners.
// ---------------------------------------------------------------------------
__global__ __launch_bounds__(256) void compact_kernel(
    const float* __restrict__ Br, const float* __restrict__ q,
    float2* __restrict__ Cb, unsigned* __restrict__ Cnt) {
  int blk = blockIdx.x;
  int bh = blk >> 3, jblk = blk & 7;
  int t = threadIdx.x;
  int jl = t >> 3, p = t & 7;
  __shared__ float Bls[32][65];
  __shared__ float qls[64];

  const float* Bbase = Br + bh * 16384 + jblk * 2048;
#pragma unroll
  for (int it = 0; it < 2; ++it) {
    int idx = it * 256 + t;
    int row = idx >> 4, c4 = (idx & 15) << 2;
    float4 v = *reinterpret_cast<const float4*>(&Bbase[row * 64 + c4]);
    Bls[row][c4 + 0] = v.x; Bls[row][c4 + 1] = v.y;
    Bls[row][c4 + 2] = v.z; Bls[row][c4 + 3] = v.w;
  }
  if (t < 64) qls[t] = q[t];
  __syncthreads();

  int c0 = p * 8;
  int nz = 0;
#pragma unroll
  for (int cc = 0; cc < 8; ++cc) {
    if (Bls[jl][c0 + cc] > 0.f) ++nz;
  }
  int incl = nz;
#pragma unroll
  for (int d = 1; d < 8; d <<= 1) {
    int u = __shfl_up(incl, d, 8);
    if (p >= d) incl += u;
  }
  int off = incl - nz;
  int total = __shfl(incl, 7, 8);

  // quad max over the 4 j's (32-thread aligned group), rounded even
  int maxq = total;
  maxq = max(maxq, __shfl_xor(maxq, 8));
  maxq = max(maxq, __shfl_xor(maxq, 16));
  maxq = (maxq + 1) & ~1;

  float2* dst = Cb + ((size_t)(bh * 64 + jblk * 8 + (jl >> 2)) << 8) + (jl & 3);
  int k = off;
#pragma unroll
  for (int cc = 0; cc < 8; ++cc) {
    int c = c0 + cc;
    float v = Bls[jl][c];
    if (v > 0.f) {
      unsigned qb = (__float_as_uint(qls[c]) & ~255u) | (unsigned)(c << 2);
      dst[(size_t)k * 4] = make_float2(v, __uint_as_float(qb));
      ++k;
    }
  }
  for (int s = total + p; s < maxq; s += 8) dst[(size_t)s * 4] = make_float2(0.f, 0.f);
  if ((t & 31) == 0) Cnt[bh * 64 + jblk * 8 + (jl >> 2)] = (unsigned)maxq;
}

// ---------------------------------------------------------------------------
// Stage 2 (sparse, POLYNOMIAL tanh, packed f32): per eval:
//   t = P(min(a*b, 4.5)), acc += q * t   — zero transcendentals, zero LUT.
// Evals packed in PAIRS across s-steps (f32x2 -> v_pk_fma_f32): per 2 evals
// ~17 pk instrs + 2 conflict-free ds_reads.  Pair lists wave-uniform -> s_load.
// Block 256 thr = 4 waves; lane = i (64-row A tile, pad-65); wave owns 2
// quads (8 j's).  grid (8 jblk, 4 isplit, 64 bh) = 2048 blocks, 8/CU.
// ---------------------------------------------------------------------------
__global__ __launch_bounds__(256, 6) void attmap_kernel(
    const float* __restrict__ Ar, const float4* __restrict__ Cb,
    const unsigned* __restrict__ Cnt, const float* __restrict__ Cf,
    float* __restrict__ rowpart, float* __restrict__ colsum) {
  int jblk = blockIdx.x, isplit = blockIdx.y, bh = blockIdx.z;
  int t = threadIdx.x;
  int il = t & 63;
  int w = __builtin_amdgcn_readfirstlane(t >> 6);  // wave id 0..3 (uniform)
  __shared__ __align__(16) float Als[64 * 65];
  __shared__ float red[256];
  __shared__ float cpart[4][8];

  const float* Abase = Ar + bh * 16384 + isplit * 4096;
#pragma unroll
  for (int it = 0; it < 4; ++it) {
    int idx = it * 256 + t;           // 1024 float4: 64 rows x 16 quads
    int r = idx >> 4, c4 = (idx & 15) << 2;
    float4 v = *reinterpret_cast<const float4*>(&Abase[r * 64 + c4]);
    Als[r * 65 + c4 + 0] = v.x; Als[r * 65 + c4 + 1] = v.y;
    Als[r * 65 + c4 + 2] = v.z; Als[r * 65 + c4 + 3] = v.w;
  }
  const float c00 = Cf[0],  c01 = Cf[1],  c02 = Cf[2],  c03 = Cf[3];
  const float c04 = Cf[4],  c05 = Cf[5],  c06 = Cf[6],  c07 = Cf[7];
  const float c08 = Cf[8],  c09 = Cf[9],  c10 = Cf[10], c11 = Cf[11];
  const float c12 = Cf[12], c13 = Cf[13], c14 = Cf[14];
  __syncthreads();

  const char* AlsB = (const char*)Als + il * 260;  // row base, stride 65 f
  const f32x2 CLAMP = {4.4995f, 4.4995f};

#define EVAL(ACC, B0, Q0, B1, Q1) do {                                       \
    float a0_ = *(const float*)(AlsB + (__float_as_uint(Q0) & 255u));        \
    float a1_ = *(const float*)(AlsB + (__float_as_uint(Q1) & 255u));        \
    f32x2 x_;  x_.x = a0_ * (B0);  x_.y = a1_ * (B1);                        \
    x_ = __builtin_elementwise_min(x_, CLAMP);                               \
    f32x2 p_ = {c14, c14};                                                   \
    p_ = x_ * p_ + (f32x2){c13, c13};                                        \
    p_ = x_ * p_ + (f32x2){c12, c12};                                        \
    p_ = x_ * p_ + (f32x2){c11, c11};                                        \
    p_ = x_ * p_ + (f32x2){c10, c10};                                        \
    p_ = x_ * p_ + (f32x2){c09, c09};                                        \
    p_ = x_ * p_ + (f32x2){c08, c08};                                        \
    p_ = x_ * p_ + (f32x2){c07, c07};                                        \
    p_ = x_ * p_ + (f32x2){c06, c06};                                        \
    p_ = x_ * p_ + (f32x2){c05, c05};                                        \
    p_ = x_ * p_ + (f32x2){c04, c04};                                        \
    p_ = x_ * p_ + (f32x2){c03, c03};                                        \
    p_ = x_ * p_ + (f32x2){c02, c02};                                        \
    p_ = x_ * p_ + (f32x2){c01, c01};                                        \
    p_ = x_ * p_ + (f32x2){c00, c00};                                        \
    f32x2 q_;  q_.x = (Q0);  q_.y = (Q1);                                    \
    ACC += q_ * p_;                                                          \
  } while (0)

  f32x2 acc[8];
#pragma unroll
  for (int jj = 0; jj < 8; ++jj) acc[jj] = (f32x2){0.f, 0.f};

#pragma unroll
  for (int qd = 0; qd < 2; ++qd) {
    int quad = bh * 64 + jblk * 8 + w * 2 + qd;       // uniform
    int n = (int)__builtin_amdgcn_readfirstlane(Cnt[quad]);  // even
    const float4* P4 = Cb + (size_t)quad * 128;       // 2 float4 per step
#pragma unroll 1
    for (int s = 0; s < n; s += 2) {
      float4 e0 = P4[s * 2 + 0];   // step s,   jj 0,1 — wave-uniform -> s_load
      float4 e1 = P4[s * 2 + 1];   // step s,   jj 2,3
      float4 e2 = P4[s * 2 + 2];   // step s+1, jj 0,1
      float4 e3 = P4[s * 2 + 3];   // step s+1, jj 2,3
      EVAL(acc[qd * 4 + 0], e0.x, e0.y, e2.x, e2.y);
      EVAL(acc[qd * 4 + 1], e0.z, e0.w, e2.z, e2.w);
      EVAL(acc[qd * 4 + 2], e1.x, e1.y, e3.x, e3.y);
      EVAL(acc[qd * 4 + 3], e1.z, e1.w, e3.z, e3.w);
    }
  }
#undef EVAL

  // row partials: lane's i gets sum over this block's 32 j's (4 waves x 8)
  float rs = 0.f;
#pragma unroll
  for (int jj = 0; jj < 8; ++jj) rs += acc[jj].x + acc[jj].y;
  red[t] = rs;

  // col sums: wave-reduce each jj over the 64 i-lanes
#pragma unroll
  for (int jj = 0; jj < 8; ++jj) {
    float v = acc[jj].x + acc[jj].y;
#pragma unroll
    for (int off = 32; off >= 1; off >>= 1) v += __shfl_xor(v, off);
    if ((t & 63) == 0) cpart[w][jj] = v;
  }
  __syncthreads();

  if (t < 64) {
    rowpart[(bh * 8 + jblk) * 256 + isplit * 64 + t] =
        red[t] + red[t + 64] + red[t + 128] + red[t + 192];
  } else if (t < 96) {
    int r = t - 64;                  // 0..31
    int ww = r >> 3, jj = r & 7;
    colsum[(bh * 4 + isplit) * 256 + jblk * 32 + ww * 8 + jj] = cpart[ww][jj];
  }
}

// ---------------------------------------------------------------------------
// Stage 3: per (bh): softmax over 256 row/col means, temps to ws, pooled
// outputs into out[0:8192].  512 threads.
// ---------------------------------------------------------------------------
__global__ __launch_bounds__(512) void softmax_pool_kernel(
    const float* __restrict__ rowpart, const float* __restrict__ colsum,
    const float* __restrict__ A0, const float* __restrict__ B0,
    float* __restrict__ b2a, float* __restrict__ a2b, float* __restrict__ out) {
  int bh = blockIdx.x;
  int b = bh >> 3, h = bh & 7;
  int t = threadIdx.x;
  int tt = t & 255;
  int lane = t & 63, w = (t >> 6) & 3;
  __shared__ float redA[4], redB[4], redC[4], redD[4];
  __shared__ float tA[256], tB[256];
  __shared__ float pp[8][64];

  float r = 0.f;
#pragma unroll
  for (int jb = 0; jb < 8; ++jb) r += rowpart[(bh * 8 + jb) * 256 + tt];
  r *= (1.f / 256.f);
  float cs = (colsum[(bh * 4 + 0) * 256 + tt] + colsum[(bh * 4 + 1) * 256 + tt] +
              colsum[(bh * 4 + 2) * 256 + tt] + colsum[(bh * 4 + 3) * 256 + tt]) *
             (1.f / 256.f);

  float mr = r, mc = cs;
#pragma unroll
  for (int off = 32; off >= 1; off >>= 1) {
    mr = fmaxf(mr, __shfl_xor(mr, off));
    mc = fmaxf(mc, __shfl_xor(mc, off));
  }
  if (lane == 0) { redA[w] = mr; redB[w] = mc; }
  __syncthreads();
  mr = fmaxf(fmaxf(redA[0], redA[1]), fmaxf(redA[2], redA[3]));
  mc = fmaxf(fmaxf(redB[0], redB[1]), fmaxf(redB[2], redB[3]));

  float er = fast_exp2((r - mr) * LOG2E);
  float ec = fast_exp2((cs - mc) * LOG2E);
  float sr = er, sc = ec;
#pragma unroll
  for (int off = 32; off >= 1; off >>= 1) {
    sr += __shfl_xor(sr, off);
    sc += __shfl_xor(sc, off);
  }
  if (lane == 0) { redC[w] = sr; redD[w] = sc; }
  __syncthreads();
  sr = redC[0] + redC[1] + redC[2] + redC[3];
  sc = redD[0] + redD[1] + redD[2] + redD[3];

  float vb2a = er * fast_rcp(sr);
  float va2b = ec * fast_rcp(sc);
  tA[tt] = vb2a; tB[tt] = va2b;
  b2a[bh * 256 + tt] = vb2a;
  a2b[bh * 256 + tt] = va2b;
  __syncthreads();

  int c = t & 63, iq = t >> 6;  // 8 groups x 32 i
  const float* Ab = A0 + b * 131072 + h * 16384;
  const float* Bb = B0 + b * 131072 + h * 16384;
  float pa = 0.f, pb = 0.f;
#pragma unroll 4
  for (int ii = 0; ii < 32; ++ii) {
    int i = (iq << 5) + ii;
    pa = fmaf(Ab[i * 64 + c], tA[i], pa);
    pb = fmaf(Bb[i * 64 + c], tB[i], pb);
  }
  pp[iq][c] = pa;
  __syncthreads();
  if (t < 64) {
    float s = 0.f;
#pragma unroll
    for (int k = 0; k < 8; ++k) s += pp[k][t];
    out[b * 1024 + h * 64 + t] = s;
  }
  __syncthreads();
  pp[iq][c] = pb;
  __syncthreads();
  if (t < 64) {
    float s = 0.f;
#pragma unroll
    for (int k = 0; k < 8; ++k) s += pp[k][t];
    out[b * 1024 + 512 + h * 64 + t] = s;
  }
}

// ---------------------------------------------------------------------------
// Stage 4: out1[b,i] = mean_h temp_b2a ; out2[b,j] = mean_h temp_a2b
// ---------------------------------------------------------------------------
__global__ __launch_bounds__(256) void mean_heads_kernel(
    const float* __restrict__ b2a, const float* __restrict__ a2b,
    float* __restrict__ out) {
  int b = blockIdx.x, t = threadIdx.x;
  float s1 = 0.f, s2 = 0.f;
#pragma unroll
  for (int h = 0; h < 8; ++h) {
    s1 += b2a[(b * 8 + h) * 256 + t];
    s2 += a2b[(b * 8 + h) * 256 + t];
  }
  out[8192 + b * 256 + t] = s1 * 0.125f;
  out[10240 + b * 256 + t] = s2 * 0.125f;
}

extern "C" void kernel_launch(void* const* d_in, const int* in_sizes, int n_in,
                              void* d_out, int out_size, void* d_ws, size_t ws_size,
                              hipStream_t stream) {
  const float* A  = (const float*)d_in[0];
  const float* B  = (const float*)d_in[1];
  const float* W1 = (const float*)d_in[2];
  const float* b1 = (const float*)d_in[3];
  const float* W2 = (const float*)d_in[4];
  const float* b2 = (const float*)d_in[5];
  const float* q  = (const float*)d_in[6];
  float* out = (float*)d_out;
  float* ws = (float*)d_ws;

  float*    Ar      = ws;                          // 1,048,576 f
  float*    Brr     = ws + 1048576;                // 1,048,576 f
  float2*   Cb      = (float2*)(ws + 2097152);     // 4096 quads * 256 f2 (8 MB)
  unsigned* Cnt     = (unsigned*)(ws + 4194304);   // 4,096 u32
  float*    Cf      = ws + 4198400;                // 16 f (poly coeffs)
  float*    rowpart = ws + 4198416;                // 64*8*256 = 131,072 f
  float*    colsum  = ws + 4329488;                // 64*4*256 = 65,536 f (~16.8 MB)
  float*    b2a     = ws;                          // alias Ar (dead after attmap)
  float*    a2b     = ws + 16384;

  fit_kernel<<<1, 64, 0, stream>>>(Cf);
  gemm_mfma_kernel<<<dim3(16, 8, 2), 256, 0, stream>>>(A, W1, b1, Ar, B, W2, b2, Brr);
  compact_kernel<<<512, 256, 0, stream>>>(Brr, q, Cb, Cnt);
  attmap_kernel<<<dim3(8, 4, 64), 256, 0, stream>>>(Ar, (const float4*)Cb, Cnt, Cf,
                                                    rowpart, colsum);
  softmax_pool_kernel<<<64, 512, 0, stream>>>(rowpart, colsum, A, B, b2a, a2b, out);
  mean_heads_kernel<<<8, 256, 0, stream>>>(b2a, a2b, out);
}

// Round 10
// 68.537 us; speedup vs baseline: 1.4501x; 1.4501x over previous
//
#include <hip/hip_runtime.h>
#include <hip/hip_bf16.h>

#define LOG2E 1.4426950408889634f
#define SC2   2.8853900817779268f   // 2*log2(e)

typedef __attribute__((ext_vector_type(8))) short short8b;   // 8 bf16 (4 VGPR)
typedef __attribute__((ext_vector_type(4))) short short4b;   // 4 bf16 (8 B)
typedef __attribute__((ext_vector_type(4))) float f32x4;

__device__ __forceinline__ float fast_exp2(float x) {
#if __has_builtin(__builtin_amdgcn_exp2f)
  return __builtin_amdgcn_exp2f(x);
#else
  return exp2f(x);
#endif
}
__device__ __forceinline__ float fast_rcp(float x) {
#if __has_builtin(__builtin_amdgcn_rcpf)
  return __builtin_amdgcn_rcpf(x);
#else
  return 1.0f / x;
#endif
}
__device__ __forceinline__ short f2bf(float f) {
  __hip_bfloat16 h = __float2bfloat16(f);
  return *reinterpret_cast<short*>(&h);
}

// ---------------------------------------------------------------------------
// Stage 1: O = relu(X @ W^T + bias) via bf16 MFMA (f32 accumulate).
// Tile 64x64, 4 waves (2x2), per-wave 32x32 = 2x2 frags of 16x16.
// grid (32, 8, 2) = 512 blocks -> 2 blocks/CU (was 1 -> latency-naked).
// ---------------------------------------------------------------------------
__global__ __launch_bounds__(256) void gemm_mfma_kernel(
    const float* __restrict__ Xa, const float* __restrict__ Wa,
    const float* __restrict__ ba, float* __restrict__ Oa,
    const float* __restrict__ Xb, const float* __restrict__ Wb,
    const float* __restrict__ bb, float* __restrict__ Ob) {
  const float* X = blockIdx.z ? Xb : Xa;
  const float* W = blockIdx.z ? Wb : Wa;
  const float* bias = blockIdx.z ? bb : ba;
  float* O = blockIdx.z ? Ob : Oa;

  __shared__ __align__(16) short As[64 * 40];  // 64 rows x 32 bf16 (+8 pad)
  __shared__ __align__(16) short Ws[64 * 40];

  int t = threadIdx.x;
  int m0 = blockIdx.x * 64, n0 = blockIdx.y * 64;
  int l = t & 63, w = t >> 6;
  int wm = (w >> 1) * 32, wn = (w & 1) * 32;
  int lr = l & 15, ko = (l >> 4) * 8;

  f32x4 acc[2][2];
#pragma unroll
  for (int m = 0; m < 2; ++m)
#pragma unroll
    for (int n = 0; n < 2; ++n) acc[m][n] = f32x4{0.f, 0.f, 0.f, 0.f};

  for (int k0 = 0; k0 < 512; k0 += 32) {
#pragma unroll
    for (int s = 0; s < 2; ++s) {
      int slot = t + s * 256;            // 512 slots: 64 rows x 8 quads
      int row = slot >> 3, q = (slot & 7) << 2;
      float4 v = *reinterpret_cast<const float4*>(&X[(m0 + row) * 512 + k0 + q]);
      short4b sv = {f2bf(v.x), f2bf(v.y), f2bf(v.z), f2bf(v.w)};
      *reinterpret_cast<short4b*>(&As[row * 40 + q]) = sv;
      float4 u = *reinterpret_cast<const float4*>(&W[(n0 + row) * 512 + k0 + q]);
      short4b su = {f2bf(u.x), f2bf(u.y), f2bf(u.z), f2bf(u.w)};
      *reinterpret_cast<short4b*>(&Ws[row * 40 + q]) = su;
    }
    __syncthreads();

    short8b afr[2], bfr[2];
#pragma unroll
    for (int m = 0; m < 2; ++m)
      afr[m] = *reinterpret_cast<const short8b*>(&As[(wm + m * 16 + lr) * 40 + ko]);
#pragma unroll
    for (int n = 0; n < 2; ++n)
      bfr[n] = *reinterpret_cast<const short8b*>(&Ws[(wn + n * 16 + lr) * 40 + ko]);
#pragma unroll
    for (int m = 0; m < 2; ++m)
#pragma unroll
      for (int n = 0; n < 2; ++n)
        acc[m][n] = __builtin_amdgcn_mfma_f32_16x16x32_bf16(afr[m], bfr[n], acc[m][n], 0, 0, 0);
    __syncthreads();
  }

#pragma unroll
  for (int n = 0; n < 2; ++n) {
    int col = n0 + wn + n * 16 + lr;
    float bv = bias[col];
#pragma unroll
    for (int m = 0; m < 2; ++m) {
      int rbase = m0 + wm + m * 16 + (l >> 4) * 4;
#pragma unroll
      for (int r = 0; r < 4; ++r) {
        float v = acc[m][n][r] + bv;
        O[(rbase + r) * 512 + col] = v > 0.f ? v : 0.f;
      }
    }
  }
}

// ---------------------------------------------------------------------------
// Stage 1.5 (r5-proven): per (bh, j) compact the nonzero B entries.
// Pair = (B*2log2e, qm) where qm = -2*q[c] with c packed into the low 6
// mantissa bits (rel perturbation 2^-17 — harmless).  Lists padded to x4
// with exact-zero pairs.  Also emits Kj = sum_{nz} q_c.
// grid 512 blocks; 256 threads = 32 j x 8 scanners; width-8 shfl prefix.
// ---------------------------------------------------------------------------
__global__ __launch_bounds__(256) void compact_kernel(
    const float* __restrict__ Br, const float* __restrict__ q,
    float2* __restrict__ Cb, unsigned* __restrict__ Cnt, float* __restrict__ Ksum) {
  int blk = blockIdx.x;
  int bh = blk >> 3, jblk = blk & 7;
  int t = threadIdx.x;
  int jl = t >> 3, p = t & 7;
  __shared__ float Bls[32][65];
  __shared__ float qls[64];

  const float* Bbase = Br + bh * 16384 + jblk * 2048;
#pragma unroll
  for (int it = 0; it < 2; ++it) {
    int idx = it * 256 + t;           // 512 float4 slots: 32 rows x 16 quads
    int row = idx >> 4, c4 = (idx & 15) << 2;
    float4 v = *reinterpret_cast<const float4*>(&Bbase[row * 64 + c4]);
    Bls[row][c4 + 0] = v.x; Bls[row][c4 + 1] = v.y;
    Bls[row][c4 + 2] = v.z; Bls[row][c4 + 3] = v.w;
  }
  if (t < 64) qls[t] = q[t];
  __syncthreads();

  int c0 = p * 8;
  int nz = 0;
  float K = 0.f;
#pragma unroll
  for (int cc = 0; cc < 8; ++cc) {
    float v = Bls[jl][c0 + cc];
    if (v > 0.f) { ++nz; K += qls[c0 + cc]; }
  }
  int incl = nz;
#pragma unroll
  for (int d = 1; d < 8; d <<= 1) {
    int u = __shfl_up(incl, d, 8);
    if (p >= d) incl += u;
  }
  int off = incl - nz;
  int total = __shfl(incl, 7, 8);

  float2* dst = Cb + (bh * 256 + jblk * 32 + jl) * 64;
  int k = off;
#pragma unroll
  for (int cc = 0; cc < 8; ++cc) {
    int c = c0 + cc;
    float v = Bls[jl][c];
    if (v > 0.f) {
      unsigned qb = (__float_as_uint(-2.f * qls[c]) & ~63u) | (unsigned)c;
      dst[k] = make_float2(v * SC2, __uint_as_float(qb));
      ++k;
    }
  }
#pragma unroll
  for (int d = 1; d < 8; d <<= 1) K += __shfl_xor(K, d, 8);

  if (p == 7) {
    int cnt = total;
    while (cnt & 3) { dst[cnt] = make_float2(0.f, 0.f); ++cnt; }
    Cnt[bh * 256 + jblk * 32 + jl] = (unsigned)cnt;
    Ksum[bh * 256 + jblk * 32 + jl] = K;
  }
}

// ---------------------------------------------------------------------------
// Stage 2 (sparse, r5 structure + DEPTH-2 SOFTWARE PIPELINE):
// M''[i,j] = sum_{s in nz(j)} qm_s * sigma(2 A_ic B_jc), rcp-PAIRED.
// The scalar pair-stream (HBM/L2-cold) is preloaded 2 iterations ahead into
// SGPRs with clamped indices (branch-free) so s_load latency hides under
// ~140cy of compute x 8 waves/SIMD.  This was the 37%-idle cause in r5-r7.
// grid (64 bh, 8 jblk, 2 isplit); 512 threads; g=t>>7 owns 8 j's, il=t&127.
// A staged [i][c] pad-65 (conflict-free dynamic-c reads).
// ---------------------------------------------------------------------------
__global__ __launch_bounds__(512, 8) void attmap_kernel(
    const float* __restrict__ Ar, const float2* __restrict__ Cb,
    const unsigned* __restrict__ Cnt,
    float* __restrict__ rowpart, float* __restrict__ colsum) {
  int bh = blockIdx.x, jblk = blockIdx.y, isplit = blockIdx.z;
  int t = threadIdx.x;
  int il = t & 127;
  int g = __builtin_amdgcn_readfirstlane(t >> 7);  // wave-uniform group id
  __shared__ __align__(16) float Als[128 * 65];
  __shared__ float red[512];
  __shared__ float cpart[8][8];

  const float* Abase = Ar + bh * 16384 + isplit * 8192;
#pragma unroll
  for (int it = 0; it < 4; ++it) {
    int idx = it * 512 + t;           // float4 slot: 128 i x 16 quads
    int r = idx >> 4, c4 = (idx & 15) << 2;
    float4 v = *reinterpret_cast<const float4*>(&Abase[r * 64 + c4]);
    Als[r * 65 + c4 + 0] = v.x; Als[r * 65 + c4 + 1] = v.y;
    Als[r * 65 + c4 + 2] = v.z; Als[r * 65 + c4 + 3] = v.w;
  }
  __syncthreads();

  const float* Arow = &Als[il * 65];
  float acc[8];

#pragma unroll
  for (int jj = 0; jj < 8; ++jj) {
    int jl = g * 8 + jj;  // uniform
    int n = (int)__builtin_amdgcn_readfirstlane(Cnt[bh * 256 + jblk * 32 + jl]);
    const float4* P4 = reinterpret_cast<const float4*>(Cb + (bh * 256 + jblk * 32 + jl) * 64);
    float s0 = 0.f, s1 = 0.f;
    if (n > 0) {
      const int nit = n >> 2;                    // >= 1, n is a multiple of 4
      float4 u0 = P4[0], v0 = P4[1];             // iter 0
      int i1 = (1 < nit) ? 1 : (nit - 1);
      float4 u1 = P4[i1 * 2], v1 = P4[i1 * 2 + 1];  // iter 1
#pragma unroll 1
      for (int it = 0; it < nit; ++it) {
        int i2 = it + 2; i2 = (i2 < nit) ? i2 : (nit - 1);
        float4 u2 = P4[i2 * 2], v2 = P4[i2 * 2 + 1];   // prefetch iter k+2
        // 4 evals on (u0, v0): pairs (u0.x/y, u0.z/w) and (v0.x/y, v0.z/w)
        float g0 = Arow[__float_as_uint(u0.y) & 63u];
        float g1 = Arow[__float_as_uint(u0.w) & 63u];
        float g2 = Arow[__float_as_uint(v0.y) & 63u];
        float g3 = Arow[__float_as_uint(v0.w) & 63u];
        float e0 = fast_exp2(g0 * u0.x);
        float e1 = fast_exp2(g1 * u0.z);
        float e2 = fast_exp2(g2 * v0.x);
        float e3 = fast_exp2(g3 * v0.z);
        float w0 = e0 + 1.f, w1 = e1 + 1.f, w2 = e2 + 1.f, w3 = e3 + 1.f;
        float n01 = fmaf(u0.w, w0, u0.y * w1);
        float n23 = fmaf(v0.w, w2, v0.y * w3);
        s0 = fmaf(n01, fast_rcp(w0 * w1), s0);
        s1 = fmaf(n23, fast_rcp(w2 * w3), s1);
        u0 = u1; v0 = v1; u1 = u2; v1 = v2;
      }
    }
    acc[jj] = s0 + s1;
  }

  float rs = 0.f;
#pragma unroll
  for (int jj = 0; jj < 8; ++jj) rs += acc[jj];
  red[t] = rs;

  int lane = t & 63, w = t >> 6;
#pragma unroll
  for (int jj = 0; jj < 8; ++jj) {
    float v = acc[jj];
#pragma unroll
    for (int off = 32; off >= 1; off >>= 1) v += __shfl_xor(v, off);
    if (lane == 0) cpart[w][jj] = v;
  }
  __syncthreads();
  if (t < 128) {
    rowpart[(bh * 8 + jblk) * 256 + isplit * 128 + t] =
        red[t] + red[t + 128] + red[t + 256] + red[t + 384];
  } else if (t < 160) {
    int jl = t - 128;
    int gg = jl >> 3, jj = jl & 7;
    colsum[(bh * 2 + isplit) * 256 + jblk * 32 + jl] =
        cpart[2 * gg][jj] + cpart[2 * gg + 1][jj];
  }
}

// ---------------------------------------------------------------------------
// Stage 3 (r5-proven): per (bh): softmax over 256 row/col means (+Kj shift on
// cols), temps to ws, pooled outputs into out[0:8192].  512 threads.
// ---------------------------------------------------------------------------
__global__ __launch_bounds__(512) void softmax_pool_kernel(
    const float* __restrict__ rowpart, const float* __restrict__ colsum,
    const float* __restrict__ Ksum,
    const float* __restrict__ A0, const float* __restrict__ B0,
    float* __restrict__ b2a, float* __restrict__ a2b, float* __restrict__ out) {
  int bh = blockIdx.x;
  int b = bh >> 3, h = bh & 7;
  int t = threadIdx.x;
  int tt = t & 255;
  int lane = t & 63, w = (t >> 6) & 3;
  __shared__ float redA[4], redB[4], redC[4], redD[4];
  __shared__ float tA[256], tB[256];
  __shared__ float pp[8][64];

  float r = 0.f;
#pragma unroll
  for (int jb = 0; jb < 8; ++jb) r += rowpart[(bh * 8 + jb) * 256 + tt];
  r *= (1.f / 256.f);
  float cs = Ksum[bh * 256 + tt] +
             (colsum[(bh * 2 + 0) * 256 + tt] + colsum[(bh * 2 + 1) * 256 + tt]) * (1.f / 256.f);

  float mr = r, mc = cs;
#pragma unroll
  for (int off = 32; off >= 1; off >>= 1) {
    mr = fmaxf(mr, __shfl_xor(mr, off));
    mc = fmaxf(mc, __shfl_xor(mc, off));
  }
  if (lane == 0) { redA[w] = mr; redB[w] = mc; }
  __syncthreads();
  mr = fmaxf(fmaxf(redA[0], redA[1]), fmaxf(redA[2], redA[3]));
  mc = fmaxf(fmaxf(redB[0], redB[1]), fmaxf(redB[2], redB[3]));

  float er = fast_exp2((r - mr) * LOG2E);
  float ec = fast_exp2((cs - mc) * LOG2E);
  float sr = er, sc = ec;
#pragma unroll
  for (int off = 32; off >= 1; off >>= 1) {
    sr += __shfl_xor(sr, off);
    sc += __shfl_xor(sc, off);
  }
  if (lane == 0) { redC[w] = sr; redD[w] = sc; }
  __syncthreads();
  sr = redC[0] + redC[1] + redC[2] + redC[3];
  sc = redD[0] + redD[1] + redD[2] + redD[3];

  float vb2a = er * fast_rcp(sr);
  float va2b = ec * fast_rcp(sc);
  tA[tt] = vb2a; tB[tt] = va2b;
  b2a[bh * 256 + tt] = vb2a;
  a2b[bh * 256 + tt] = va2b;
  __syncthreads();

  int c = t & 63, iq = t >> 6;  // 8 groups x 32 i
  const float* Ab = A0 + b * 131072 + h * 16384;
  const float* Bb = B0 + b * 131072 + h * 16384;
  float pa = 0.f, pb = 0.f;
#pragma unroll 4
  for (int ii = 0; ii < 32; ++ii) {
    int i = (iq << 5) + ii;
    pa = fmaf(Ab[i * 64 + c], tA[i], pa);
    pb = fmaf(Bb[i * 64 + c], tB[i], pb);
  }
  pp[iq][c] = pa;
  __syncthreads();
  if (t < 64) {
    float s = 0.f;
#pragma unroll
    for (int k = 0; k < 8; ++k) s += pp[k][t];
    out[b * 1024 + h * 64 + t] = s;
  }
  __syncthreads();
  pp[iq][c] = pb;
  __syncthreads();
  if (t < 64) {
    float s = 0.f;
#pragma unroll
    for (int k = 0; k < 8; ++k) s += pp[k][t];
    out[b * 1024 + 512 + h * 64 + t] = s;
  }
}

// ---------------------------------------------------------------------------
// Stage 4: out1[b,i] = mean_h temp_b2a ; out2[b,j] = mean_h temp_a2b
// ---------------------------------------------------------------------------
__global__ __launch_bounds__(256) void mean_heads_kernel(
    const float* __restrict__ b2a, const float* __restrict__ a2b,
    float* __restrict__ out) {
  int b = blockIdx.x, t = threadIdx.x;
  float s1 = 0.f, s2 = 0.f;
#pragma unroll
  for (int h = 0; h < 8; ++h) {
    s1 += b2a[(b * 8 + h) * 256 + t];
    s2 += a2b[(b * 8 + h) * 256 + t];
  }
  out[8192 + b * 256 + t] = s1 * 0.125f;
  out[10240 + b * 256 + t] = s2 * 0.125f;
}

extern "C" void kernel_launch(void* const* d_in, const int* in_sizes, int n_in,
                              void* d_out, int out_size, void* d_ws, size_t ws_size,
                              hipStream_t stream) {
  const float* A  = (const float*)d_in[0];
  const float* B  = (const float*)d_in[1];
  const float* W1 = (const float*)d_in[2];
  const float* b1 = (const float*)d_in[3];
  const float* W2 = (const float*)d_in[4];
  const float* b2 = (const float*)d_in[5];
  const float* q  = (const float*)d_in[6];
  float* out = (float*)d_out;
  float* ws = (float*)d_ws;

  float*    Ar      = ws;                          // 1,048,576 f
  float*    Brr     = ws + 1048576;                // 1,048,576 f
  float2*   Cb      = (float2*)(ws + 2097152);     // 1,048,576 f2 (8 MB)
  unsigned* Cnt     = (unsigned*)(ws + 4194304);   // 16,384 u32
  float*    Ksum    = ws + 4210688;                // 16,384 f
  float*    rowpart = ws + 4227072;                // 131,072 f
  float*    colsum  = ws + 4358144;                // 32,768 f  (end ~17.6 MB)
  float*    b2a     = ws;                          // alias Ar (dead after attmap)
  float*    a2b     = ws + 16384;

  gemm_mfma_kernel<<<dim3(32, 8, 2), 256, 0, stream>>>(A, W1, b1, Ar, B, W2, b2, Brr);
  compact_kernel<<<512, 256, 0, stream>>>(Brr, q, Cb, Cnt, Ksum);
  attmap_kernel<<<dim3(64, 8, 2), 512, 0, stream>>>(Ar, Cb, Cnt, rowpart, colsum);
  softmax_pool_kernel<<<64, 512, 0, stream>>>(rowpart, colsum, Ksum, A, B, b2a, a2b, out);
  mean_heads_kernel<<<8, 256, 0, stream>>>(b2a, a2b, out);
}

// Round 12
// 64.426 us; speedup vs baseline: 1.5427x; 1.0638x over previous
//
#include <hip/hip_runtime.h>
#include <hip/hip_bf16.h>

#define LOG2E 1.4426950408889634f
#define SC2   2.8853900817779268f   // 2*log2(e)

typedef __attribute__((ext_vector_type(8))) short short8b;   // 8 bf16 (4 VGPR)
typedef __attribute__((ext_vector_type(4))) short short4b;   // 4 bf16 (8 B)
typedef __attribute__((ext_vector_type(4))) float f32x4;

__device__ __forceinline__ float fast_exp2(float x) {
#if __has_builtin(__builtin_amdgcn_exp2f)
  return __builtin_amdgcn_exp2f(x);
#else
  return exp2f(x);
#endif
}
__device__ __forceinline__ float fast_rcp(float x) {
#if __has_builtin(__builtin_amdgcn_rcpf)
  return __builtin_amdgcn_rcpf(x);
#else
  return 1.0f / x;
#endif
}
__device__ __forceinline__ short f2bf(float f) {
  __hip_bfloat16 h = __float2bfloat16(f);
  return *reinterpret_cast<short*>(&h);
}

// ---------------------------------------------------------------------------
// Stage 1 (+fused compact): O = relu(X @ W^T + bias) via bf16 MFMA.
// Tile 64x64, 4 waves (2x2), per-wave 32x32 = 2x2 frags of 16x16.
// z=0 (A path): write dense Ar to HBM (attmap stages it into LDS).
// z=1 (B path): relu tile -> LDS -> in-block compact to the r5-proven pair
//   stream.  RAW-RESHAPE MAPPING (the r11 bug): matrix row r, col = n0+cc
//   maps to bh = (r>>8)*8 + ((r>>5)&7), j = ((r&31)<<3) + (n0>>6), c = cc.
//   Pair=(B*2log2e, qm), qm=-2*q[c] with c in the low 6 mantissa bits;
//   lists padded to x4 with zero pairs; Cnt + Ksum (sum_{nz} q_c) emitted.
// ---------------------------------------------------------------------------
__global__ __launch_bounds__(256) void gemm_fused_kernel(
    const float* __restrict__ Xa, const float* __restrict__ Wa,
    const float* __restrict__ ba, float* __restrict__ Oa,
    const float* __restrict__ Xb, const float* __restrict__ Wb,
    const float* __restrict__ bb, const float* __restrict__ q,
    float2* __restrict__ Cb, unsigned* __restrict__ Cnt,
    float* __restrict__ Ksum) {
  const int isB = blockIdx.z;
  const float* X = isB ? Xb : Xa;
  const float* W = isB ? Wb : Wa;
  const float* bias = isB ? bb : ba;

  __shared__ __align__(16) short As[64 * 40];  // 64 rows x 32 bf16 (+8 pad)
  __shared__ __align__(16) short Ws[64 * 40];
  __shared__ __align__(16) float Btile[64][65];
  __shared__ float qls[64];

  int t = threadIdx.x;
  int m0 = blockIdx.x * 64, n0 = blockIdx.y * 64;
  int l = t & 63, w = t >> 6;
  int wm = (w >> 1) * 32, wn = (w & 1) * 32;
  int lr = l & 15, ko = (l >> 4) * 8;

  if (isB && t < 64) qls[t] = q[t];

  f32x4 acc[2][2];
#pragma unroll
  for (int m = 0; m < 2; ++m)
#pragma unroll
    for (int n = 0; n < 2; ++n) acc[m][n] = f32x4{0.f, 0.f, 0.f, 0.f};

  for (int k0 = 0; k0 < 512; k0 += 32) {
#pragma unroll
    for (int s = 0; s < 2; ++s) {
      int slot = t + s * 256;            // 512 slots: 64 rows x 8 quads
      int row = slot >> 3, qd = (slot & 7) << 2;
      float4 v = *reinterpret_cast<const float4*>(&X[(m0 + row) * 512 + k0 + qd]);
      short4b sv = {f2bf(v.x), f2bf(v.y), f2bf(v.z), f2bf(v.w)};
      *reinterpret_cast<short4b*>(&As[row * 40 + qd]) = sv;
      float4 u = *reinterpret_cast<const float4*>(&W[(n0 + row) * 512 + k0 + qd]);
      short4b su = {f2bf(u.x), f2bf(u.y), f2bf(u.z), f2bf(u.w)};
      *reinterpret_cast<short4b*>(&Ws[row * 40 + qd]) = su;
    }
    __syncthreads();

    short8b afr[2], bfr[2];
#pragma unroll
    for (int m = 0; m < 2; ++m)
      afr[m] = *reinterpret_cast<const short8b*>(&As[(wm + m * 16 + lr) * 40 + ko]);
#pragma unroll
    for (int n = 0; n < 2; ++n)
      bfr[n] = *reinterpret_cast<const short8b*>(&Ws[(wn + n * 16 + lr) * 40 + ko]);
#pragma unroll
    for (int m = 0; m < 2; ++m)
#pragma unroll
      for (int n = 0; n < 2; ++n)
        acc[m][n] = __builtin_amdgcn_mfma_f32_16x16x32_bf16(afr[m], bfr[n], acc[m][n], 0, 0, 0);
    __syncthreads();
  }

  if (!isB) {
    // A path: dense store.  C/D layout: col = lane&15, row = (lane>>4)*4 + r
#pragma unroll
    for (int n = 0; n < 2; ++n) {
      int col = n0 + wn + n * 16 + lr;
      float bv = bias[col];
#pragma unroll
      for (int m = 0; m < 2; ++m) {
        int rbase = m0 + wm + m * 16 + (l >> 4) * 4;
#pragma unroll
        for (int r = 0; r < 4; ++r) {
          float v = acc[m][n][r] + bv;
          Oa[(rbase + r) * 512 + col] = v > 0.f ? v : 0.f;
        }
      }
    }
    return;
  }

  // B path: relu tile -> LDS, then in-block compact.
#pragma unroll
  for (int n = 0; n < 2; ++n) {
    int col = wn + n * 16 + lr;
    float bv = bias[n0 + col];
#pragma unroll
    for (int m = 0; m < 2; ++m) {
      int rbase = wm + m * 16 + (l >> 4) * 4;
#pragma unroll
      for (int r = 0; r < 4; ++r) {
        float v = acc[m][n][r] + bv;
        Btile[rbase + r][col] = v > 0.f ? v : 0.f;
      }
    }
  }
  __syncthreads();

  // compact: 256 thr = 64 tile-rows x 4 scanners of 16 c each.
  int jl = t >> 2, p = t & 3;          // tile row, scanner
  int row = m0 + jl;                   // matrix row
  int bh = (row >> 8) * 8 + ((row >> 5) & 7);
  int j = ((row & 31) << 3) + (n0 >> 6);
  int c0 = p * 16;

  int nz = 0;
  float K = 0.f;
#pragma unroll
  for (int cc = 0; cc < 16; ++cc) {
    float v = Btile[jl][c0 + cc];
    if (v > 0.f) { ++nz; K += qls[c0 + cc]; }
  }
  int incl = nz;
#pragma unroll
  for (int d = 1; d < 4; d <<= 1) {
    int u = __shfl_up(incl, d, 4);
    if (p >= d) incl += u;
  }
  int off = incl - nz;
  int total = __shfl(incl, 3, 4);

  float2* dst = Cb + (bh * 256 + j) * 64;
  int k = off;
#pragma unroll
  for (int cc = 0; cc < 16; ++cc) {
    int c = c0 + cc;
    float v = Btile[jl][c];
    if (v > 0.f) {
      unsigned qb = (__float_as_uint(-2.f * qls[c]) & ~63u) | (unsigned)c;
      dst[k] = make_float2(v * SC2, __uint_as_float(qb));
      ++k;
    }
  }
  K += __shfl_xor(K, 1, 4);
  K += __shfl_xor(K, 2, 4);
  if (p == 3) {
    int cnt = total;
    while (cnt & 3) { dst[cnt] = make_float2(0.f, 0.f); ++cnt; }
    Cnt[bh * 256 + j] = (unsigned)cnt;
    Ksum[bh * 256 + j] = K;
  }
}

// ---------------------------------------------------------------------------
// Stage 2 (r10-proven, unchanged): sparse sigma with rcp-pairing and depth-2
// pipelined scalar pair-loads.  grid (64 bh, 8 jblk, 2 isplit); 512 threads.
// ---------------------------------------------------------------------------
__global__ __launch_bounds__(512, 8) void attmap_kernel(
    const float* __restrict__ Ar, const float2* __restrict__ Cb,
    const unsigned* __restrict__ Cnt,
    float* __restrict__ rowpart, float* __restrict__ colsum) {
  int bh = blockIdx.x, jblk = blockIdx.y, isplit = blockIdx.z;
  int t = threadIdx.x;
  int il = t & 127;
  int g = __builtin_amdgcn_readfirstlane(t >> 7);  // wave-uniform group id
  __shared__ __align__(16) float Als[128 * 65];
  __shared__ float red[512];
  __shared__ float cpart[8][8];

  const float* Abase = Ar + bh * 16384 + isplit * 8192;
#pragma unroll
  for (int it = 0; it < 4; ++it) {
    int idx = it * 512 + t;           // float4 slot: 128 i x 16 quads
    int r = idx >> 4, c4 = (idx & 15) << 2;
    float4 v = *reinterpret_cast<const float4*>(&Abase[r * 64 + c4]);
    Als[r * 65 + c4 + 0] = v.x; Als[r * 65 + c4 + 1] = v.y;
    Als[r * 65 + c4 + 2] = v.z; Als[r * 65 + c4 + 3] = v.w;
  }
  __syncthreads();

  const float* Arow = &Als[il * 65];
  float acc[8];

#pragma unroll
  for (int jj = 0; jj < 8; ++jj) {
    int jl = g * 8 + jj;  // uniform
    int n = (int)__builtin_amdgcn_readfirstlane(Cnt[bh * 256 + jblk * 32 + jl]);
    const float4* P4 = reinterpret_cast<const float4*>(Cb + (bh * 256 + jblk * 32 + jl) * 64);
    float s0 = 0.f, s1 = 0.f;
    if (n > 0) {
      const int nit = n >> 2;                    // >= 1, n is a multiple of 4
      float4 u0 = P4[0], v0 = P4[1];             // iter 0
      int i1 = (1 < nit) ? 1 : (nit - 1);
      float4 u1 = P4[i1 * 2], v1 = P4[i1 * 2 + 1];  // iter 1
#pragma unroll 1
      for (int it = 0; it < nit; ++it) {
        int i2 = it + 2; i2 = (i2 < nit) ? i2 : (nit - 1);
        float4 u2 = P4[i2 * 2], v2 = P4[i2 * 2 + 1];   // prefetch iter k+2
        float g0 = Arow[__float_as_uint(u0.y) & 63u];
        float g1 = Arow[__float_as_uint(u0.w) & 63u];
        float g2 = Arow[__float_as_uint(v0.y) & 63u];
        float g3 = Arow[__float_as_uint(v0.w) & 63u];
        float e0 = fast_exp2(g0 * u0.x);
        float e1 = fast_exp2(g1 * u0.z);
        float e2 = fast_exp2(g2 * v0.x);
        float e3 = fast_exp2(g3 * v0.z);
        float w0 = e0 + 1.f, w1 = e1 + 1.f, w2 = e2 + 1.f, w3 = e3 + 1.f;
        float n01 = fmaf(u0.w, w0, u0.y * w1);
        float n23 = fmaf(v0.w, w2, v0.y * w3);
        s0 = fmaf(n01, fast_rcp(w0 * w1), s0);
        s1 = fmaf(n23, fast_rcp(w2 * w3), s1);
        u0 = u1; v0 = v1; u1 = u2; v1 = v2;
      }
    }
    acc[jj] = s0 + s1;
  }

  float rs = 0.f;
#pragma unroll
  for (int jj = 0; jj < 8; ++jj) rs += acc[jj];
  red[t] = rs;

  int lane = t & 63, w = t >> 6;
#pragma unroll
  for (int jj = 0; jj < 8; ++jj) {
    float v = acc[jj];
#pragma unroll
    for (int off = 32; off >= 1; off >>= 1) v += __shfl_xor(v, off);
    if (lane == 0) cpart[w][jj] = v;
  }
  __syncthreads();
  if (t < 128) {
    rowpart[(bh * 8 + jblk) * 256 + isplit * 128 + t] =
        red[t] + red[t + 128] + red[t + 256] + red[t + 384];
  } else if (t < 160) {
    int jl = t - 128;
    int gg = jl >> 3, jj = jl & 7;
    colsum[(bh * 2 + isplit) * 256 + jblk * 32 + jl] =
        cpart[2 * gg][jj] + cpart[2 * gg + 1][jj];
  }
}

// ---------------------------------------------------------------------------
// Stage 3 (split 4-way for CU utilization): grid (64 bh, 4 chunk), 512 thr.
// Each block redundantly computes the cheap softmax (reads ~18 KB), then
// pools only its 64-i chunk; partials to poolA/poolB.  chunk 0 also writes
// the b2a/a2b temps used by the final kernel's head-mean outputs.
// ---------------------------------------------------------------------------
__global__ __launch_bounds__(512) void softmax_pool_kernel(
    const float* __restrict__ rowpart, const float* __restrict__ colsum,
    const float* __restrict__ Ksum,
    const float* __restrict__ A0, const float* __restrict__ B0,
    float* __restrict__ b2a, float* __restrict__ a2b,
    float* __restrict__ poolA, float* __restrict__ poolB) {
  int bh = blockIdx.x, chunk = blockIdx.y;
  int b = bh >> 3, h = bh & 7;
  int t = threadIdx.x;
  int tt = t & 255;
  int lane = t & 63, w = (t >> 6) & 3;
  __shared__ float redA[4], redB[4], redC[4], redD[4];
  __shared__ float tA[256], tB[256];
  __shared__ float pp[8][64];

  float r = 0.f;
#pragma unroll
  for (int jb = 0; jb < 8; ++jb) r += rowpart[(bh * 8 + jb) * 256 + tt];
  r *= (1.f / 256.f);
  float cs = Ksum[bh * 256 + tt] +
             (colsum[(bh * 2 + 0) * 256 + tt] + colsum[(bh * 2 + 1) * 256 + tt]) * (1.f / 256.f);

  float mr = r, mc = cs;
#pragma unroll
  for (int off = 32; off >= 1; off >>= 1) {
    mr = fmaxf(mr, __shfl_xor(mr, off));
    mc = fmaxf(mc, __shfl_xor(mc, off));
  }
  if (lane == 0) { redA[w] = mr; redB[w] = mc; }
  __syncthreads();
  mr = fmaxf(fmaxf(redA[0], redA[1]), fmaxf(redA[2], redA[3]));
  mc = fmaxf(fmaxf(redB[0], redB[1]), fmaxf(redB[2], redB[3]));

  float er = fast_exp2((r - mr) * LOG2E);
  float ec = fast_exp2((cs - mc) * LOG2E);
  float sr = er, sc = ec;
#pragma unroll
  for (int off = 32; off >= 1; off >>= 1) {
    sr += __shfl_xor(sr, off);
    sc += __shfl_xor(sc, off);
  }
  if (lane == 0) { redC[w] = sr; redD[w] = sc; }
  __syncthreads();
  sr = redC[0] + redC[1] + redC[2] + redC[3];
  sc = redD[0] + redD[1] + redD[2] + redD[3];

  float vb2a = er * fast_rcp(sr);
  float va2b = ec * fast_rcp(sc);
  tA[tt] = vb2a; tB[tt] = va2b;
  if (chunk == 0) {
    b2a[bh * 256 + tt] = vb2a;
    a2b[bh * 256 + tt] = va2b;
  }
  __syncthreads();

  // pool this chunk's 64 i's: 512 thr = 64 c x 8 isub (8 i's each)
  int c = t & 63, isub = t >> 6;
  const float* Ab = A0 + b * 131072 + h * 16384;
  const float* Bb = B0 + b * 131072 + h * 16384;
  float pa = 0.f, pb = 0.f;
#pragma unroll
  for (int ii = 0; ii < 8; ++ii) {
    int i = chunk * 64 + isub * 8 + ii;
    pa = fmaf(Ab[i * 64 + c], tA[i], pa);
    pb = fmaf(Bb[i * 64 + c], tB[i], pb);
  }
  pp[isub][c] = pa;
  __syncthreads();
  if (t < 64) {
    float s = 0.f;
#pragma unroll
    for (int k = 0; k < 8; ++k) s += pp[k][t];
    poolA[(bh * 4 + chunk) * 64 + t] = s;
  }
  __syncthreads();
  pp[isub][c] = pb;
  __syncthreads();
  if (t < 64) {
    float s = 0.f;
#pragma unroll
    for (int k = 0; k < 8; ++k) s += pp[k][t];
    poolB[(bh * 4 + chunk) * 64 + t] = s;
  }
}

// ---------------------------------------------------------------------------
// Stage 4: combine pool partials into out[0:8192] and head-means into
// out[8192:12288].  grid (8 b), 256 thr.
// ---------------------------------------------------------------------------
__global__ __launch_bounds__(256) void final_kernel(
    const float* __restrict__ poolA, const float* __restrict__ poolB,
    const float* __restrict__ b2a, const float* __restrict__ a2b,
    float* __restrict__ out) {
  int b = blockIdx.x, t = threadIdx.x;
  float s1 = 0.f, s2 = 0.f;
#pragma unroll
  for (int h = 0; h < 8; ++h) {
    s1 += b2a[(b * 8 + h) * 256 + t];
    s2 += a2b[(b * 8 + h) * 256 + t];
  }
  out[8192 + b * 256 + t] = s1 * 0.125f;
  out[10240 + b * 256 + t] = s2 * 0.125f;

#pragma unroll
  for (int hh = 0; hh < 2; ++hh) {
    int idx = hh * 256 + t;
    int h = idx >> 6, c = idx & 63;
    int base = ((b * 8 + h) * 4) * 64 + c;
    float sA = poolA[base] + poolA[base + 64] + poolA[base + 128] + poolA[base + 192];
    float sB = poolB[base] + poolB[base + 64] + poolB[base + 128] + poolB[base + 192];
    out[b * 1024 + h * 64 + c] = sA;
    out[b * 1024 + 512 + h * 64 + c] = sB;
  }
}

extern "C" void kernel_launch(void* const* d_in, const int* in_sizes, int n_in,
                              void* d_out, int out_size, void* d_ws, size_t ws_size,
                              hipStream_t stream) {
  const float* A  = (const float*)d_in[0];
  const float* B  = (const float*)d_in[1];
  const float* W1 = (const float*)d_in[2];
  const float* b1 = (const float*)d_in[3];
  const float* W2 = (const float*)d_in[4];
  const float* b2 = (const float*)d_in[5];
  const float* q  = (const float*)d_in[6];
  float* out = (float*)d_out;
  float* ws = (float*)d_ws;

  float*    Ar      = ws;                          // 1,048,576 f (4 MB)
  float2*   Cb      = (float2*)(ws + 1048576);     // 1,048,576 f2 (8 MB)
  unsigned* Cnt     = (unsigned*)(ws + 3145728);   // 16,384 u32
  float*    Ksum    = ws + 3162112;                // 16,384 f
  float*    rowpart = ws + 3178496;                // 131,072 f
  float*    colsum  = ws + 3309568;                // 32,768 f
  float*    b2a     = ws + 3342336;                // 16,384 f
  float*    a2b     = ws + 3358720;                // 16,384 f
  float*    poolA   = ws + 3375104;                // 16,384 f
  float*    poolB   = ws + 3391488;                // 16,384 f (end ~13.6 MB)

  gemm_fused_kernel<<<dim3(32, 8, 2), 256, 0, stream>>>(
      A, W1, b1, Ar, B, W2, b2, q, Cb, Cnt, Ksum);
  attmap_kernel<<<dim3(64, 8, 2), 512, 0, stream>>>(Ar, Cb, Cnt, rowpart, colsum);
  softmax_pool_kernel<<<dim3(64, 4), 512, 0, stream>>>(
      rowpart, colsum, Ksum, A, B, b2a, a2b, poolA, poolB);
  final_kernel<<<8, 256, 0, stream>>>(poolA, poolB, b2a, a2b, out);
}